// Round 2
// baseline (1254.930 us; speedup 1.0000x reference)
//
#include <hip/hip_runtime.h>
#include <math.h>

// ---------------- types ----------------
typedef __bf16 bf16x8 __attribute__((ext_vector_type(8)));
typedef float  floatx4 __attribute__((ext_vector_type(4)));
typedef unsigned short ushort8v __attribute__((ext_vector_type(8)));

__device__ inline float bf_lo(unsigned u){ return __uint_as_float(u << 16); }
__device__ inline float bf_hi(unsigned u){ return __uint_as_float(u & 0xffff0000u); }
__device__ inline unsigned short f2bf_u(float f){
    unsigned u = __float_as_uint(f);
    return (unsigned short)((u + 0x7fffu + ((u >> 16) & 1u)) >> 16);   // RNE
}
__device__ inline unsigned pack2(float a, float b){
    return (unsigned)f2bf_u(a) | ((unsigned)f2bf_u(b) << 16);
}
__device__ inline float gelu_f(float v){
    return 0.5f * v * (1.f + erff(v * 0.70710678118654752f));
}

// ---------------- utility: zero fill (graph-capture-safe replacement for memset) ----------------
__global__ void zero_k(int* __restrict__ p, int n){
    int i = blockIdx.x * 256 + threadIdx.x;
    if (i < n) p[i] = 0;
}

// ---------------- weight transpose + bf16 convert: Wt[n][k] = W[k][n] ----------------
__global__ void wprep_k(const float* __restrict__ W, unsigned short* __restrict__ Wt,
                        int K, int Ncols){
    int idx = blockIdx.x * 256 + threadIdx.x;
    if (idx < K * Ncols){
        int k = idx / Ncols, n = idx - k * Ncols;
        Wt[(size_t)n * K + k] = f2bf_u(W[idx]);
    }
}

// ---------------- CSR build ----------------
__global__ void hist_k(const int* __restrict__ dst, int* __restrict__ indeg, int E){
    int i = blockIdx.x * 256 + threadIdx.x;
    if (i < E) atomicAdd(&indeg[dst[i]], 1);
}

__global__ void scan1_k(const int* __restrict__ indeg, int* __restrict__ csum, int N){
    __shared__ int sd[256];
    const int base = blockIdx.x * 2048;
    int s = 0;
    for (int j = 0; j < 8; ++j){
        int i = base + j * 256 + threadIdx.x;
        if (i < N) s += indeg[i];
    }
    sd[threadIdx.x] = s; __syncthreads();
    for (int d = 128; d > 0; d >>= 1){
        if (threadIdx.x < d) sd[threadIdx.x] += sd[threadIdx.x + d];
        __syncthreads();
    }
    if (threadIdx.x == 0) csum[blockIdx.x] = sd[0];
}

__global__ void scan2_k(int* csum, int nch){
    if (threadIdx.x == 0 && blockIdx.x == 0){
        int run = 0;
        for (int i = 0; i < nch; ++i){ int v = csum[i]; csum[i] = run; run += v; }
    }
}

__global__ void scan3_k(const int* __restrict__ indeg, const int* __restrict__ csum,
                        int* __restrict__ offsets, int* __restrict__ cursor, int N, int E){
    __shared__ int ss[256];
    const int base = blockIdx.x * 2048;
    int v[8], pre[8]; int s = 0;
    const int tb = base + threadIdx.x * 8;
#pragma unroll
    for (int j = 0; j < 8; ++j){
        int i = tb + j;
        v[j] = (i < N) ? indeg[i] : 0;
        pre[j] = s; s += v[j];
    }
    ss[threadIdx.x] = s; __syncthreads();
    for (int d = 1; d < 256; d <<= 1){
        int t_ = (threadIdx.x >= d) ? ss[threadIdx.x - d] : 0;
        __syncthreads();
        ss[threadIdx.x] += t_;
        __syncthreads();
    }
    const int excl = ss[threadIdx.x] - s + csum[blockIdx.x];
#pragma unroll
    for (int j = 0; j < 8; ++j){
        int i = tb + j;
        if (i < N){ offsets[i] = excl + pre[j]; cursor[i] = excl + pre[j]; }
    }
    if (blockIdx.x == 0 && threadIdx.x == 0) offsets[N] = E;
}

__global__ void fill_k(const int* __restrict__ src, const int* __restrict__ dst,
                       int* __restrict__ cursor, int* __restrict__ esrc, int E){
    int i = blockIdx.x * 256 + threadIdx.x;
    if (i < E){
        int d = dst[i];
        int pos = atomicAdd(&cursor[d], 1);
        esrc[pos] = src[i];
    }
}

// ---------------- aggregation: agg[n] = sum_{e: dst=n} h_bn[src(e)]  (GH=256 fixed) ----------------
__global__ __launch_bounds__(256)
void agg_k(const unsigned short* __restrict__ hbn, const int* __restrict__ offsets,
           const int* __restrict__ esrc, unsigned short* __restrict__ aggout, int N){
    const int lane = threadIdx.x & 63;
    const int node = blockIdx.x * 4 + (threadIdx.x >> 6);
    if (node >= N) return;
    const int off = offsets[node];
    const int end = offsets[node + 1];
    float a0 = 0.f, a1 = 0.f, a2 = 0.f, a3 = 0.f;
    for (int c = off; c < end; c += 64){
        const int e = c + lane;
        int sl = (e < end) ? esrc[e] : 0;
        const int cnt = min(64, end - c);
        for (int j = 0; j < cnt; ++j){
            const int s = __shfl(sl, j);
            const uint2 u = *(const uint2*)(hbn + (size_t)s * 256 + lane * 4);
            a0 += bf_lo(u.x); a1 += bf_hi(u.x);
            a2 += bf_lo(u.y); a3 += bf_hi(u.y);
        }
    }
    uint2 o; o.x = pack2(a0, a1); o.y = pack2(a2, a3);
    *(uint2*)(aggout + (size_t)node * 256 + lane * 4) = o;
}

// ---------------- GEMM: C[M,Ncols](bf16) = A[M,K] @ W[K,Ncols] + bias, optional 2nd A@W, gelu, BN-stats ----------------
// Bt is W^T bf16 [Ncols][K]. BM=256 (4 waves x 64 rows), BN=64, BK=64, B K-tile 128.
// MFMA 16x16x32 bf16; A frag: m=lane&15, k=(lane>>4)*8+j ; C/D: col=lane&15, row=(lane>>4)*4+reg.
template<bool A_F32, bool DUAL, bool GELU_OUT, bool STATS>
__global__ __launch_bounds__(256, 2)
void gemm_k(const void* __restrict__ Av, const void* __restrict__ A2v,
            const unsigned short* __restrict__ Bt, const unsigned short* __restrict__ Bt2,
            const float* __restrict__ bias, unsigned short* __restrict__ Cp,
            float* __restrict__ gsum, float* __restrict__ gsq,
            int M, int K, int Ncols){
    __shared__ unsigned short As[256][72];    // 64 cols + 8 pad (2-way bank alias: free)
    __shared__ unsigned short Bs[64][136];    // 128 cols + 8 pad
    __shared__ float s_sum[64], s_sq[64];

    const int t    = threadIdx.x;
    const int lane = t & 63;
    const int wave = t >> 6;
    const int mb   = blockIdx.x;
    const int nb   = blockIdx.y;
    const int r16  = lane & 15;
    const int kofs = (lane >> 4) * 8;

    floatx4 acc[4][4];
#pragma unroll
    for (int mi = 0; mi < 4; ++mi)
#pragma unroll
        for (int ni = 0; ni < 4; ++ni) acc[mi][ni] = (floatx4)0.f;

    const int nph = DUAL ? 2 : 1;
    for (int ph = 0; ph < nph; ++ph){
        const unsigned short* Ab  = (const unsigned short*)(ph ? A2v : Av);
        const float*          Af  = (const float*)Av;
        const unsigned short* Btp = ph ? Bt2 : Bt;
        for (int kt = 0; kt < K; kt += 128){
            const int ktlen  = (K - kt < 128) ? (K - kt) : 128;
            const int cpr    = ktlen >> 3;
            const int cshift = (ktlen == 128) ? 4 : 3;
            const int totalB = 64 * cpr;
            for (int idx = t; idx < totalB; idx += 256){
                const int row = idx >> cshift;
                const int kc8 = (idx & (cpr - 1)) << 3;
                ushort8v v = *(const ushort8v*)(Btp + (size_t)(nb * 64 + row) * K + kt + kc8);
                *(ushort8v*)(&Bs[row][kc8]) = v;
            }
            for (int k0l = 0; k0l < ktlen; k0l += 64){
                const int k0 = kt + k0l;
#pragma unroll
                for (int it = 0; it < 8; ++it){
                    const int idx = it * 256 + t;
                    const int row = idx >> 3;
                    const int kc8 = (idx & 7) << 3;
                    const int gm  = mb * 256 + row;
                    ushort8v v;
                    if (gm < M){
                        if constexpr (A_F32){
                            const float4* p = (const float4*)(Af + (size_t)gm * K + k0 + kc8);
                            float4 f0 = p[0], f1 = p[1];
                            v[0] = f2bf_u(f0.x); v[1] = f2bf_u(f0.y); v[2] = f2bf_u(f0.z); v[3] = f2bf_u(f0.w);
                            v[4] = f2bf_u(f1.x); v[5] = f2bf_u(f1.y); v[6] = f2bf_u(f1.z); v[7] = f2bf_u(f1.w);
                        } else {
                            v = *(const ushort8v*)(Ab + (size_t)gm * K + k0 + kc8);
                        }
                    } else {
                        v = (ushort8v)0;
                    }
                    *(ushort8v*)(&As[row][kc8]) = v;
                }
                __syncthreads();
#pragma unroll
                for (int kc = 0; kc < 64; kc += 32){
                    bf16x8 afr[4], bfr[4];
#pragma unroll
                    for (int mi = 0; mi < 4; ++mi)
                        afr[mi] = *(const bf16x8*)(&As[wave * 64 + mi * 16 + r16][kc + kofs]);
#pragma unroll
                    for (int ni = 0; ni < 4; ++ni)
                        bfr[ni] = *(const bf16x8*)(&Bs[ni * 16 + r16][k0l + kc + kofs]);
#pragma unroll
                    for (int mi = 0; mi < 4; ++mi)
#pragma unroll
                        for (int ni = 0; ni < 4; ++ni)
                            acc[mi][ni] = __builtin_amdgcn_mfma_f32_16x16x32_bf16(
                                afr[mi], bfr[ni], acc[mi][ni], 0, 0, 0);
                }
                __syncthreads();
            }
        }
    }

    // ---- epilogue: bias (+gelu), store bf16, fused BN column stats ----
    if constexpr (STATS){ if (t < 64){ s_sum[t] = 0.f; s_sq[t] = 0.f; } }
    __syncthreads();
    int   gncol[4]; float bv[4];
#pragma unroll
    for (int ni = 0; ni < 4; ++ni){ gncol[ni] = nb * 64 + ni * 16 + r16; bv[ni] = bias[gncol[ni]]; }
    float csum[4] = {0,0,0,0}, csq[4] = {0,0,0,0};
    const int rbase = wave * 64 + (lane >> 4) * 4;
#pragma unroll
    for (int mi = 0; mi < 4; ++mi){
#pragma unroll
        for (int r = 0; r < 4; ++r){
            const int gm = mb * 256 + rbase + mi * 16 + r;
            if (gm < M){
                const size_t rowoff = (size_t)gm * Ncols;
#pragma unroll
                for (int ni = 0; ni < 4; ++ni){
                    float v = acc[mi][ni][r] + bv[ni];
                    if constexpr (GELU_OUT) v = gelu_f(v);
                    Cp[rowoff + gncol[ni]] = f2bf_u(v);
                    if constexpr (STATS){ csum[ni] += v; csq[ni] += v * v; }
                }
            }
        }
    }
    if constexpr (STATS){
#pragma unroll
        for (int ni = 0; ni < 4; ++ni){
            atomicAdd(&s_sum[ni * 16 + r16], csum[ni]);
            atomicAdd(&s_sq [ni * 16 + r16], csq[ni]);
        }
        __syncthreads();
        if (t < 64){
            atomicAdd(&gsum[nb * 64 + t], s_sum[t]);
            atomicAdd(&gsq [nb * 64 + t], s_sq[t]);
        }
    }
}

// ---------------- BN apply (+gelu, +residual, fp32/bf16 out) ----------------
template<bool GELU_OUT, bool RES, bool RES_F32, bool OUT_F32>
__global__ __launch_bounds__(256)
void bn_apply_k(const unsigned short* __restrict__ in, void* __restrict__ outv,
                const void* __restrict__ resv,
                const float* __restrict__ gsum, const float* __restrict__ gsq,
                const float* __restrict__ gamma, const float* __restrict__ beta,
                size_t total, int Ncols, float invN){
    __shared__ float s_scale[512], s_shift[512];
    for (int c = threadIdx.x; c < Ncols; c += 256){
        float mean = gsum[c] * invN;
        float var  = gsq[c] * invN - mean * mean;
        float sc   = gamma[c] * rsqrtf(var + 1e-5f);
        s_scale[c] = sc;
        s_shift[c] = beta[c] - mean * sc;
    }
    __syncthreads();
    size_t i8 = ((size_t)blockIdx.x * 256 + threadIdx.x) * 8;
    if (i8 >= total) return;
    const int col0 = (int)(i8 % (size_t)Ncols);
    uint4 u = *(const uint4*)(in + i8);
    float v[8];
    v[0] = bf_lo(u.x); v[1] = bf_hi(u.x); v[2] = bf_lo(u.y); v[3] = bf_hi(u.y);
    v[4] = bf_lo(u.z); v[5] = bf_hi(u.z); v[6] = bf_lo(u.w); v[7] = bf_hi(u.w);
#pragma unroll
    for (int j = 0; j < 8; ++j){
        v[j] = v[j] * s_scale[col0 + j] + s_shift[col0 + j];
        if constexpr (GELU_OUT) v[j] = gelu_f(v[j]);
    }
    if constexpr (RES){
        if constexpr (RES_F32){
            const float4* rp = (const float4*)((const float*)resv + i8);
            float4 r0 = rp[0], r1 = rp[1];
            v[0] += r0.x; v[1] += r0.y; v[2] += r0.z; v[3] += r0.w;
            v[4] += r1.x; v[5] += r1.y; v[6] += r1.z; v[7] += r1.w;
        } else {
            uint4 r = *(const uint4*)((const unsigned short*)resv + i8);
            v[0] += bf_lo(r.x); v[1] += bf_hi(r.x); v[2] += bf_lo(r.y); v[3] += bf_hi(r.y);
            v[4] += bf_lo(r.z); v[5] += bf_hi(r.z); v[6] += bf_lo(r.w); v[7] += bf_hi(r.w);
        }
    }
    if constexpr (OUT_F32){
        float4* op = (float4*)((float*)outv + i8);
        op[0] = make_float4(v[0], v[1], v[2], v[3]);
        op[1] = make_float4(v[4], v[5], v[6], v[7]);
    } else {
        uint4 o;
        o.x = pack2(v[0], v[1]); o.y = pack2(v[2], v[3]);
        o.z = pack2(v[4], v[5]); o.w = pack2(v[6], v[7]);
        *(uint4*)((unsigned short*)outv + i8) = o;
    }
}

// ---------------- host ----------------
extern "C" void kernel_launch(void* const* d_in, const int* in_sizes, int n_in,
                              void* d_out, int out_size, void* d_ws, size_t ws_size,
                              hipStream_t stream){
    const int C = 192, GH = 256, FH = 512;
    const float* x    = (const float*)d_in[0];
    const int*   ei   = (const int*)d_in[1];
    const float* Wg1  = (const float*)d_in[2];
    const float* bg1  = (const float*)d_in[3];
    const float* gg1  = (const float*)d_in[4];
    const float* beg1 = (const float*)d_in[5];
    const float* Wrel = (const float*)d_in[6];
    const float* brel = (const float*)d_in[7];
    const float* Wroot= (const float*)d_in[8];
    const float* Wg2  = (const float*)d_in[9];
    const float* bg2  = (const float*)d_in[10];
    const float* gg2  = (const float*)d_in[11];
    const float* beg2 = (const float*)d_in[12];
    const float* Wf1  = (const float*)d_in[13];
    const float* bf1  = (const float*)d_in[14];
    const float* gf1  = (const float*)d_in[15];
    const float* bef1 = (const float*)d_in[16];
    const float* Wf2  = (const float*)d_in[17];
    const float* bf2  = (const float*)d_in[18];
    const float* gf2  = (const float*)d_in[19];
    const float* bef2 = (const float*)d_in[20];

    const int N = in_sizes[0] / C;
    const int E = in_sizes[1] / 2;
    const int* e_src = ei;
    const int* e_dst = ei + E;

    // ---- compact workspace arena (~201 MB total; lifetimes annotated) ----
    char* wp = (char*)d_ws;
    auto carve = [&](size_t bytes) -> void* {
        void* p = (void*)wp; wp += (bytes + 255) & ~(size_t)255; return p;
    };
    unsigned short* wt_g1  = (unsigned short*)carve((size_t)C * GH * 2);
    unsigned short* wt_rel = (unsigned short*)carve((size_t)GH * GH * 2);
    unsigned short* wt_root= (unsigned short*)carve((size_t)GH * GH * 2);
    unsigned short* wt_g2  = (unsigned short*)carve((size_t)GH * C * 2);
    unsigned short* wt_f1  = (unsigned short*)carve((size_t)C * FH * 2);
    unsigned short* wt_f2  = (unsigned short*)carve((size_t)FH * C * 2);
    float* stats = (float*)carve(2 * (size_t)(GH + C + FH + C) * 4);
    float* sum1 = stats;        float* sq1 = sum1 + GH;
    float* sum2 = sq1 + GH;     float* sq2 = sum2 + C;
    float* sum3 = sq2 + C;      float* sq3 = sum3 + FH;
    float* sum4 = sq3 + FH;     float* sq4 = sum4 + C;
    int* indeg   = (int*)carve((size_t)N * 4);
    int* offsets = (int*)carve((size_t)(N + 1) * 4);
    int* cursor  = (int*)carve((size_t)(N + 1) * 4);
    const int nch = (N + 2047) / 2048;
    int* csum    = (int*)carve((size_t)nch * 4);
    int* esrc    = (int*)carve((size_t)E * 4);
    // buf0 [N,GH]: h1 -> hbn (in-place BN); later h2 [N,C] -> x2 (in-place BN+res)
    unsigned short* buf0  = (unsigned short*)carve((size_t)N * GH * 2);
    // buf12 [N,FH] contiguous: lower [N,GH]=agg, upper [N,GH]=g; later whole = f1 -> g2 (in-place)
    unsigned short* buf12 = (unsigned short*)carve((size_t)N * FH * 2);
    // buf3 [N,C]: h4
    unsigned short* buf3  = (unsigned short*)carve((size_t)N * C * 2);
    unsigned short* h1  = buf0;
    unsigned short* hbn = buf0;
    unsigned short* aggb = buf12;
    unsigned short* g    = buf12 + (size_t)N * GH;
    unsigned short* h2   = buf0;
    unsigned short* x2   = buf0;
    unsigned short* f1   = buf12;
    unsigned short* g2   = buf12;
    unsigned short* h4   = buf3;
    (void)ws_size; (void)n_in; (void)out_size;

    const float invN = 1.0f / (float)N;
    const int MB = (N + 255) / 256;
    const int EB = (E + 255) / 256;

    // weight prep (every call — ws is re-poisoned)
    wprep_k<<<(C * GH + 255) / 256, 256, 0, stream>>>(Wg1, wt_g1, C, GH);
    wprep_k<<<(GH * GH + 255) / 256, 256, 0, stream>>>(Wrel, wt_rel, GH, GH);
    wprep_k<<<(GH * GH + 255) / 256, 256, 0, stream>>>(Wroot, wt_root, GH, GH);
    wprep_k<<<(GH * C + 255) / 256, 256, 0, stream>>>(Wg2, wt_g2, GH, C);
    wprep_k<<<(C * FH + 255) / 256, 256, 0, stream>>>(Wf1, wt_f1, C, FH);
    wprep_k<<<(FH * C + 255) / 256, 256, 0, stream>>>(Wf2, wt_f2, FH, C);

    // zero stats + indeg (kernel, not memset — capture-safe)
    const int nstats = 2 * (GH + C + FH + C);
    zero_k<<<(nstats + 255) / 256, 256, 0, stream>>>((int*)stats, nstats);
    zero_k<<<(N + 255) / 256, 256, 0, stream>>>(indeg, N);

    // CSR build
    hist_k<<<EB, 256, 0, stream>>>(e_dst, indeg, E);
    scan1_k<<<nch, 256, 0, stream>>>(indeg, csum, N);
    scan2_k<<<1, 64, 0, stream>>>(csum, nch);
    scan3_k<<<nch, 256, 0, stream>>>(indeg, csum, offsets, cursor, N, E);
    fill_k<<<EB, 256, 0, stream>>>(e_src, e_dst, cursor, esrc, E);

    // Grapher
    gemm_k<true, false, false, true><<<dim3(MB, GH / 64), 256, 0, stream>>>(
        x, nullptr, wt_g1, nullptr, bg1, h1, sum1, sq1, N, C, GH);
    bn_apply_k<false, false, false, false><<<(int)(((size_t)N * GH / 8 + 255) / 256), 256, 0, stream>>>(
        h1, hbn, nullptr, sum1, sq1, gg1, beg1, (size_t)N * GH, GH, invN);
    agg_k<<<(N + 3) / 4, 256, 0, stream>>>(hbn, offsets, esrc, aggb, N);
    gemm_k<false, true, true, false><<<dim3(MB, GH / 64), 256, 0, stream>>>(
        aggb, hbn, wt_rel, wt_root, brel, g, nullptr, nullptr, N, GH, GH);
    gemm_k<false, false, false, true><<<dim3(MB, C / 64), 256, 0, stream>>>(
        g, nullptr, wt_g2, nullptr, bg2, h2, sum2, sq2, N, GH, C);
    bn_apply_k<false, true, true, false><<<(int)(((size_t)N * C / 8 + 255) / 256), 256, 0, stream>>>(
        h2, x2, x, sum2, sq2, gg2, beg2, (size_t)N * C, C, invN);

    // FFN
    gemm_k<false, false, false, true><<<dim3(MB, FH / 64), 256, 0, stream>>>(
        x2, nullptr, wt_f1, nullptr, bf1, f1, sum3, sq3, N, C, FH);
    bn_apply_k<true, false, false, false><<<(int)(((size_t)N * FH / 8 + 255) / 256), 256, 0, stream>>>(
        f1, g2, nullptr, sum3, sq3, gf1, bef1, (size_t)N * FH, FH, invN);
    gemm_k<false, false, false, true><<<dim3(MB, C / 64), 256, 0, stream>>>(
        g2, nullptr, wt_f2, nullptr, bf2, h4, sum4, sq4, N, FH, C);
    bn_apply_k<false, true, false, true><<<(int)(((size_t)N * C / 8 + 255) / 256), 256, 0, stream>>>(
        h4, d_out, x2, sum4, sq4, gf2, bef2, (size_t)N * C, C, invN);
}

// Round 3
// 1113.803 us; speedup vs baseline: 1.1267x; 1.1267x over previous
//
#include <hip/hip_runtime.h>
#include <math.h>

// ---------------- types ----------------
typedef __bf16 bf16x8 __attribute__((ext_vector_type(8)));
typedef float  floatx4 __attribute__((ext_vector_type(4)));
typedef unsigned short ushort8v __attribute__((ext_vector_type(8)));

__device__ inline float bf_lo(unsigned u){ return __uint_as_float(u << 16); }
__device__ inline float bf_hi(unsigned u){ return __uint_as_float(u & 0xffff0000u); }
__device__ inline unsigned short f2bf_u(float f){
    unsigned u = __float_as_uint(f);
    return (unsigned short)((u + 0x7fffu + ((u >> 16) & 1u)) >> 16);   // RNE
}
__device__ inline unsigned pack2(float a, float b){
    return (unsigned)f2bf_u(a) | ((unsigned)f2bf_u(b) << 16);
}
__device__ inline float gelu_f(float v){
    return 0.5f * v * (1.f + erff(v * 0.70710678118654752f));
}

// ---------------- utility: zero fill ----------------
__global__ void zero_k(int* __restrict__ p, int n){
    int i = blockIdx.x * 256 + threadIdx.x;
    if (i < n) p[i] = 0;
}

// ---------------- weight transpose + bf16: Wt[n*ostride + ooffs + k] = W[k][n] ----------------
__global__ void wprep_k(const float* __restrict__ W, unsigned short* __restrict__ Wt,
                        int K, int Ncols, int ostride, int ooffs){
    int idx = blockIdx.x * 256 + threadIdx.x;
    if (idx < K * Ncols){
        int k = idx / Ncols, n = idx - k * Ncols;
        Wt[(size_t)n * ostride + ooffs + k] = f2bf_u(W[idx]);
    }
}

// ---------------- CSR build ----------------
__global__ void hist_k(const int* __restrict__ dst, int* __restrict__ indeg, int E){
    int i = blockIdx.x * 256 + threadIdx.x;
    if (i < E) atomicAdd(&indeg[dst[i]], 1);
}

__global__ void scan1_k(const int* __restrict__ indeg, int* __restrict__ csum, int N){
    __shared__ int sd[256];
    const int base = blockIdx.x * 2048;
    int s = 0;
    for (int j = 0; j < 8; ++j){
        int i = base + j * 256 + threadIdx.x;
        if (i < N) s += indeg[i];
    }
    sd[threadIdx.x] = s; __syncthreads();
    for (int d = 128; d > 0; d >>= 1){
        if (threadIdx.x < d) sd[threadIdx.x] += sd[threadIdx.x + d];
        __syncthreads();
    }
    if (threadIdx.x == 0) csum[blockIdx.x] = sd[0];
}

__global__ void scan2_k(int* csum, int nch){
    if (threadIdx.x == 0 && blockIdx.x == 0){
        int run = 0;
        for (int i = 0; i < nch; ++i){ int v = csum[i]; csum[i] = run; run += v; }
    }
}

__global__ void scan3_k(const int* __restrict__ indeg, const int* __restrict__ csum,
                        int* __restrict__ offsets, int* __restrict__ cursor, int N, int E){
    __shared__ int ss[256];
    const int base = blockIdx.x * 2048;
    int v[8], pre[8]; int s = 0;
    const int tb = base + threadIdx.x * 8;
#pragma unroll
    for (int j = 0; j < 8; ++j){
        int i = tb + j;
        v[j] = (i < N) ? indeg[i] : 0;
        pre[j] = s; s += v[j];
    }
    ss[threadIdx.x] = s; __syncthreads();
    for (int d = 1; d < 256; d <<= 1){
        int t_ = (threadIdx.x >= d) ? ss[threadIdx.x - d] : 0;
        __syncthreads();
        ss[threadIdx.x] += t_;
        __syncthreads();
    }
    const int excl = ss[threadIdx.x] - s + csum[blockIdx.x];
#pragma unroll
    for (int j = 0; j < 8; ++j){
        int i = tb + j;
        if (i < N){ offsets[i] = excl + pre[j]; cursor[i] = excl + pre[j]; }
    }
    if (blockIdx.x == 0 && threadIdx.x == 0) offsets[N] = E;
}

__global__ void fill_k(const int* __restrict__ src, const int* __restrict__ dst,
                       int* __restrict__ cursor, int* __restrict__ esrc, int E){
    int i = blockIdx.x * 256 + threadIdx.x;
    if (i < E){
        int d = dst[i];
        int pos = atomicAdd(&cursor[d], 1);
        esrc[pos] = src[i];
    }
}

// ---------------- aggregation into AG[:,0:256]; hbn = AG+256, both row-stride 512 ----------------
__global__ __launch_bounds__(256)
void agg_k(const unsigned short* __restrict__ hbn, const int* __restrict__ offsets,
           const int* __restrict__ esrc, unsigned short* __restrict__ aggout, int N){
    const int lane = threadIdx.x & 63;
    const int node = blockIdx.x * 4 + (threadIdx.x >> 6);
    if (node >= N) return;
    const int off = offsets[node];
    const int end = offsets[node + 1];
    float a0 = 0.f, a1 = 0.f, a2 = 0.f, a3 = 0.f;
    for (int c = off; c < end; c += 64){
        const int e = c + lane;
        int sl = (e < end) ? esrc[e] : 0;
        const int cnt = min(64, end - c);
        for (int j = 0; j < cnt; ++j){
            const int s = __shfl(sl, j);
            const uint2 u = *(const uint2*)(hbn + (size_t)s * 512 + lane * 4);
            a0 += bf_lo(u.x); a1 += bf_hi(u.x);
            a2 += bf_lo(u.y); a3 += bf_hi(u.y);
        }
    }
    uint2 o; o.x = pack2(a0, a1); o.y = pack2(a2, a3);
    *(uint2*)(aggout + (size_t)node * 512 + lane * 4) = o;
}

// ---------------- GEMM v2: BM=64, A LDS-resident (full K), B from L2, barrier-free K-loop ----------
// Bt[n][k] bf16, row stride K. 4 waves split the N dimension.
// MFMA 16x16x32 bf16: A frag m=lane&15, k=(lane>>4)*8+j; C/D col=lane&15, row=(lane>>4)*4+reg.
template<int K, int NCOLS, bool A_F32, bool GELU_OUT, bool STATS>
__global__ __launch_bounds__(256)
void gemm2_k(const void* __restrict__ Av, const unsigned short* __restrict__ Bt,
             const float* __restrict__ bias, unsigned short* __restrict__ Cp,
             float* __restrict__ gsum, float* __restrict__ gsq, int M){
    constexpr int KP = K + 8;
    constexpr int NI = (NCOLS >= 256) ? 4 : NCOLS / 64;   // 192->3, 256->4, 512->4
    constexpr int NPASS = NCOLS / (64 * NI);              // 192->1, 256->1, 512->2
    __shared__ unsigned short As[64][KP];
    __shared__ float s_stat[STATS ? 2 * NCOLS : 2];

    const int t    = threadIdx.x;
    const int lane = t & 63;
    const int wn   = t >> 6;
    const int r16  = lane & 15;
    const int q4   = lane >> 4;
    const int kofs = q4 * 8;
    const long mbase = (long)blockIdx.x * 64;

    if constexpr (STATS)
        for (int c = t; c < 2 * NCOLS; c += 256) s_stat[c] = 0.f;

    // ---- stage A (64 x K) once ----
    {
        const unsigned short* Ab = (const unsigned short*)Av;
        const float*          Af = (const float*)Av;
        constexpr int CPR = K / 8;
        constexpr int AIT = 64 * CPR / 256;   // K/32
#pragma unroll
        for (int it = 0; it < AIT; ++it){
            int idx = it * 256 + t;
            int row = idx / CPR;
            int kc8 = (idx - row * CPR) * 8;
            long gm = mbase + row;
            ushort8v v;
            if (gm < M){
                if constexpr (A_F32){
                    const float4* p = (const float4*)(Af + gm * K + kc8);
                    float4 f0 = p[0], f1 = p[1];
                    v[0] = f2bf_u(f0.x); v[1] = f2bf_u(f0.y); v[2] = f2bf_u(f0.z); v[3] = f2bf_u(f0.w);
                    v[4] = f2bf_u(f1.x); v[5] = f2bf_u(f1.y); v[6] = f2bf_u(f1.z); v[7] = f2bf_u(f1.w);
                } else {
                    v = *(const ushort8v*)(Ab + gm * K + kc8);
                }
            } else {
                v = (ushort8v)0;
            }
            *(ushort8v*)(&As[row][kc8]) = v;
        }
    }
    __syncthreads();

    for (int np = 0; np < NPASS; ++np){
        const int cb = np * 256 + wn * (16 * NI);
        floatx4 acc[4][NI];
#pragma unroll
        for (int mi = 0; mi < 4; ++mi)
#pragma unroll
            for (int ni = 0; ni < NI; ++ni) acc[mi][ni] = (floatx4)0.f;

        const unsigned short* bp = Bt + (size_t)(cb + r16) * K + kofs;
#pragma unroll
        for (int kc = 0; kc < K; kc += 32){
            bf16x8 afr[4], bfr[NI];
#pragma unroll
            for (int mi = 0; mi < 4; ++mi)
                afr[mi] = *(const bf16x8*)(&As[mi * 16 + r16][kc + kofs]);
#pragma unroll
            for (int ni = 0; ni < NI; ++ni)
                bfr[ni] = *(const bf16x8*)(bp + (size_t)ni * 16 * K + kc);
#pragma unroll
            for (int mi = 0; mi < 4; ++mi)
#pragma unroll
                for (int ni = 0; ni < NI; ++ni)
                    acc[mi][ni] = __builtin_amdgcn_mfma_f32_16x16x32_bf16(
                        afr[mi], bfr[ni], acc[mi][ni], 0, 0, 0);
        }

        // epilogue: bias (+gelu), bf16 store, per-column stats
        float bv[NI];
#pragma unroll
        for (int ni = 0; ni < NI; ++ni) bv[ni] = bias[cb + ni * 16 + r16];
        float csum[NI], csq[NI];
#pragma unroll
        for (int ni = 0; ni < NI; ++ni){ csum[ni] = 0.f; csq[ni] = 0.f; }
#pragma unroll
        for (int mi = 0; mi < 4; ++mi){
#pragma unroll
            for (int r = 0; r < 4; ++r){
                long gm = mbase + mi * 16 + q4 * 4 + r;
                if (gm < M){
                    size_t rowoff = (size_t)gm * NCOLS + cb;
#pragma unroll
                    for (int ni = 0; ni < NI; ++ni){
                        float v = acc[mi][ni][r] + bv[ni];
                        if constexpr (GELU_OUT) v = gelu_f(v);
                        Cp[rowoff + ni * 16 + r16] = f2bf_u(v);
                        if constexpr (STATS){ csum[ni] += v; csq[ni] += v * v; }
                    }
                }
            }
        }
        if constexpr (STATS){
#pragma unroll
            for (int ni = 0; ni < NI; ++ni){
                atomicAdd(&s_stat[cb + ni * 16 + r16], csum[ni]);
                atomicAdd(&s_stat[NCOLS + cb + ni * 16 + r16], csq[ni]);
            }
        }
    }
    if constexpr (STATS){
        __syncthreads();
        for (int c = t; c < NCOLS; c += 256){
            atomicAdd(&gsum[c], s_stat[c]);
            atomicAdd(&gsq[c],  s_stat[NCOLS + c]);
        }
    }
}

// ---------------- BN apply (+gelu, +residual, strided out, fp32/bf16 out) ----------------
template<int NCOLS, bool GELU_OUT, bool RES, bool RES_F32, bool OUT_F32>
__global__ __launch_bounds__(256)
void bn_apply_k(const unsigned short* __restrict__ in, void* __restrict__ outv,
                const void* __restrict__ resv,
                const float* __restrict__ gsum, const float* __restrict__ gsq,
                const float* __restrict__ gamma, const float* __restrict__ beta,
                long nrows, int ostride, int ooffs, float invN){
    __shared__ float s_scale[NCOLS], s_shift[NCOLS];
    for (int c = threadIdx.x; c < NCOLS; c += 256){
        float mean = gsum[c] * invN;
        float var  = gsq[c] * invN - mean * mean;
        float sc   = gamma[c] * rsqrtf(var + 1e-5f);
        s_scale[c] = sc;
        s_shift[c] = beta[c] - mean * sc;
    }
    __syncthreads();
    long i8 = ((long)blockIdx.x * 256 + threadIdx.x) * 8;
    if (i8 >= nrows * (long)NCOLS) return;
    long row  = i8 / NCOLS;
    int  col0 = (int)(i8 - row * NCOLS);
    uint4 u = *(const uint4*)(in + i8);
    float v[8];
    v[0] = bf_lo(u.x); v[1] = bf_hi(u.x); v[2] = bf_lo(u.y); v[3] = bf_hi(u.y);
    v[4] = bf_lo(u.z); v[5] = bf_hi(u.z); v[6] = bf_lo(u.w); v[7] = bf_hi(u.w);
#pragma unroll
    for (int j = 0; j < 8; ++j){
        v[j] = v[j] * s_scale[col0 + j] + s_shift[col0 + j];
        if constexpr (GELU_OUT) v[j] = gelu_f(v[j]);
    }
    if constexpr (RES){
        if constexpr (RES_F32){
            const float4* rp = (const float4*)((const float*)resv + i8);
            float4 r0 = rp[0], r1 = rp[1];
            v[0] += r0.x; v[1] += r0.y; v[2] += r0.z; v[3] += r0.w;
            v[4] += r1.x; v[5] += r1.y; v[6] += r1.z; v[7] += r1.w;
        } else {
            uint4 r = *(const uint4*)((const unsigned short*)resv + i8);
            v[0] += bf_lo(r.x); v[1] += bf_hi(r.x); v[2] += bf_lo(r.y); v[3] += bf_hi(r.y);
            v[4] += bf_lo(r.z); v[5] += bf_hi(r.z); v[6] += bf_lo(r.w); v[7] += bf_hi(r.w);
        }
    }
    long opos = row * ostride + ooffs + col0;
    if constexpr (OUT_F32){
        float4* op = (float4*)((float*)outv + opos);
        op[0] = make_float4(v[0], v[1], v[2], v[3]);
        op[1] = make_float4(v[4], v[5], v[6], v[7]);
    } else {
        uint4 o;
        o.x = pack2(v[0], v[1]); o.y = pack2(v[2], v[3]);
        o.z = pack2(v[4], v[5]); o.w = pack2(v[6], v[7]);
        *(uint4*)((unsigned short*)outv + opos) = o;
    }
}

// ---------------- host ----------------
extern "C" void kernel_launch(void* const* d_in, const int* in_sizes, int n_in,
                              void* d_out, int out_size, void* d_ws, size_t ws_size,
                              hipStream_t stream){
    const int C = 192, GH = 256, FH = 512;
    const float* x    = (const float*)d_in[0];
    const int*   ei   = (const int*)d_in[1];
    const float* Wg1  = (const float*)d_in[2];
    const float* bg1  = (const float*)d_in[3];
    const float* gg1  = (const float*)d_in[4];
    const float* beg1 = (const float*)d_in[5];
    const float* Wrel = (const float*)d_in[6];
    const float* brel = (const float*)d_in[7];
    const float* Wroot= (const float*)d_in[8];
    const float* Wg2  = (const float*)d_in[9];
    const float* bg2  = (const float*)d_in[10];
    const float* gg2  = (const float*)d_in[11];
    const float* beg2 = (const float*)d_in[12];
    const float* Wf1  = (const float*)d_in[13];
    const float* bf1  = (const float*)d_in[14];
    const float* gf1  = (const float*)d_in[15];
    const float* bef1 = (const float*)d_in[16];
    const float* Wf2  = (const float*)d_in[17];
    const float* bf2  = (const float*)d_in[18];
    const float* gf2  = (const float*)d_in[19];
    const float* bef2 = (const float*)d_in[20];

    const int N = in_sizes[0] / C;
    const int E = in_sizes[1] / 2;
    const int* e_src = ei;
    const int* e_dst = ei + E;

    // ---- workspace arena (~214 MB) ----
    char* wp = (char*)d_ws;
    auto carve = [&](size_t bytes) -> void* {
        void* p = (void*)wp; wp += (bytes + 255) & ~(size_t)255; return p;
    };
    unsigned short* wt_g1 = (unsigned short*)carve((size_t)GH * C * 2);     // [256][192]
    unsigned short* wt_rr = (unsigned short*)carve((size_t)GH * 512 * 2);   // [256][512] = [Wrel^T | Wroot^T]
    unsigned short* wt_g2 = (unsigned short*)carve((size_t)C * GH * 2);     // [192][256]
    unsigned short* wt_f1 = (unsigned short*)carve((size_t)FH * C * 2);     // [512][192]
    unsigned short* wt_f2 = (unsigned short*)carve((size_t)C * FH * 2);     // [192][512]
    float* stats = (float*)carve(2 * (size_t)(GH + C + FH + C) * 4);
    float* sum1 = stats;        float* sq1 = sum1 + GH;
    float* sum2 = sq1 + GH;     float* sq2 = sum2 + C;
    float* sum3 = sq2 + C;      float* sq3 = sum3 + FH;
    float* sum4 = sq3 + FH;     float* sq4 = sum4 + C;
    int* indeg   = (int*)carve((size_t)N * 4);
    int* offsets = (int*)carve((size_t)(N + 1) * 4);
    int* cursor  = (int*)carve((size_t)(N + 1) * 4);
    const int nch = (N + 2047) / 2048;
    int* csum    = (int*)carve((size_t)nch * 4);
    int* esrc    = (int*)carve((size_t)E * 4);
    // buf0 [N,512]: h1[N,256] -> g[N,256] -> f1/g2[N,512]
    unsigned short* buf0  = (unsigned short*)carve((size_t)N * 512 * 2);
    // bufAG [N,512]: AG=[agg|hbn] -> h2/x2 [N,192] at 0, h4 [N,192] at N*192
    unsigned short* bufAG = (unsigned short*)carve((size_t)N * 512 * 2);
    unsigned short* h1  = buf0;
    unsigned short* g   = buf0;
    unsigned short* f1  = buf0;      // also g2 (in-place BN)
    unsigned short* AG  = bufAG;
    unsigned short* h2  = bufAG;     // also x2 (in-place BN+res)
    unsigned short* h4  = bufAG + (size_t)N * C;
    (void)ws_size; (void)n_in; (void)out_size;

    const float invN = 1.0f / (float)N;
    const int GB = (N + 63) / 64;     // gemm grid
    const int EB = (E + 255) / 256;

    // weight prep
    wprep_k<<<(C * GH + 255) / 256, 256, 0, stream>>>(Wg1, wt_g1, C, GH, C, 0);
    wprep_k<<<(GH * GH + 255) / 256, 256, 0, stream>>>(Wrel, wt_rr, GH, GH, 512, 0);
    wprep_k<<<(GH * GH + 255) / 256, 256, 0, stream>>>(Wroot, wt_rr, GH, GH, 512, GH);
    wprep_k<<<(GH * C + 255) / 256, 256, 0, stream>>>(Wg2, wt_g2, GH, C, GH, 0);
    wprep_k<<<(C * FH + 255) / 256, 256, 0, stream>>>(Wf1, wt_f1, C, FH, C, 0);
    wprep_k<<<(FH * C + 255) / 256, 256, 0, stream>>>(Wf2, wt_f2, FH, C, FH, 0);

    const int nstats = 2 * (GH + C + FH + C);
    zero_k<<<(nstats + 255) / 256, 256, 0, stream>>>((int*)stats, nstats);
    zero_k<<<(N + 255) / 256, 256, 0, stream>>>(indeg, N);

    // CSR build
    hist_k<<<EB, 256, 0, stream>>>(e_dst, indeg, E);
    scan1_k<<<nch, 256, 0, stream>>>(indeg, csum, N);
    scan2_k<<<1, 64, 0, stream>>>(csum, nch);
    scan3_k<<<nch, 256, 0, stream>>>(indeg, csum, offsets, cursor, N, E);
    fill_k<<<EB, 256, 0, stream>>>(e_src, e_dst, cursor, esrc, E);

    // ---- Grapher ----
    // h1 = x @ Wg1 + bg1   (fp32 A, stats)
    gemm2_k<192, 256, true, false, true><<<GB, 256, 0, stream>>>(
        x, wt_g1, bg1, h1, sum1, sq1, N);
    // hbn = BN(h1) -> AG[:,256:512]
    bn_apply_k<256, false, false, false, false><<<(int)(((size_t)N * GH / 8 + 255) / 256), 256, 0, stream>>>(
        h1, AG, nullptr, sum1, sq1, gg1, beg1, N, 512, 256, invN);
    // agg -> AG[:,0:256]
    agg_k<<<(N + 3) / 4, 256, 0, stream>>>(AG + 256, offsets, esrc, AG, N);
    // g = gelu([agg|hbn] @ [Wrel;Wroot] + brel)   (K=512 single GEMM)
    gemm2_k<512, 256, false, true, false><<<GB, 256, 0, stream>>>(
        AG, wt_rr, brel, g, nullptr, nullptr, N);
    // h2 = g @ Wg2 + bg2   (stats)
    gemm2_k<256, 192, false, false, true><<<GB, 256, 0, stream>>>(
        g, wt_g2, bg2, h2, sum2, sq2, N);
    // x2 = BN(h2) + x      (in-place, res fp32)
    bn_apply_k<192, false, true, true, false><<<(int)(((size_t)N * C / 8 + 255) / 256), 256, 0, stream>>>(
        h2, h2, x, sum2, sq2, gg2, beg2, N, 192, 0, invN);

    // ---- FFN ----
    // f1 = x2 @ Wf1 + bf1  (stats)
    gemm2_k<192, 512, false, false, true><<<GB, 256, 0, stream>>>(
        h2, wt_f1, bf1, f1, sum3, sq3, N);
    // g2 = gelu(BN(f1))    (in-place)
    bn_apply_k<512, true, false, false, false><<<(int)(((size_t)N * FH / 8 + 255) / 256), 256, 0, stream>>>(
        f1, f1, nullptr, sum3, sq3, gf1, bef1, N, 512, 0, invN);
    // h4 = g2 @ Wf2 + bf2  (stats)
    gemm2_k<512, 192, false, false, true><<<GB, 256, 0, stream>>>(
        f1, wt_f2, bf2, h4, sum4, sq4, N);
    // out = BN(h4) + x2    (fp32 out)
    bn_apply_k<192, false, true, false, true><<<(int)(((size_t)N * C / 8 + 255) / 256), 256, 0, stream>>>(
        h4, d_out, h2, sum4, sq4, gf2, bef2, N, 192, 0, invN);
}

// Round 4
// 980.359 us; speedup vs baseline: 1.2801x; 1.1361x over previous
//
#include <hip/hip_runtime.h>
#include <math.h>

// ---------------- types ----------------
typedef __bf16 bf16x8 __attribute__((ext_vector_type(8)));
typedef float  floatx4 __attribute__((ext_vector_type(4)));

__device__ inline float bf_lo(unsigned u){ return __uint_as_float(u << 16); }
__device__ inline float bf_hi(unsigned u){ return __uint_as_float(u & 0xffff0000u); }
__device__ inline unsigned short f2bf_u(float f){
    unsigned u = __float_as_uint(f);
    return (unsigned short)((u + 0x7fffu + ((u >> 16) & 1u)) >> 16);   // RNE
}
__device__ inline unsigned pack2(float a, float b){
    return (unsigned)f2bf_u(a) | ((unsigned)f2bf_u(b) << 16);
}
__device__ inline float gelu_f(float v){
    return 0.5f * v * (1.f + erff(v * 0.70710678118654752f));
}
__device__ inline void gload_lds16(const void* g, void* l){
    __builtin_amdgcn_global_load_lds(
        (const __attribute__((address_space(1))) unsigned int*)g,
        (__attribute__((address_space(3))) unsigned int*)l, 16, 0, 0);
}

// ---------------- utility ----------------
__global__ void zero_k(int* __restrict__ p, int n){
    int i = blockIdx.x * 256 + threadIdx.x;
    if (i < n) p[i] = 0;
}

__global__ void xcast_k(const float* __restrict__ x, unsigned short* __restrict__ xb, long n8){
    long i = (long)blockIdx.x * 256 + threadIdx.x;
    if (i < n8){
        const float4* p = (const float4*)(x + i * 8);
        float4 a = p[0], b = p[1];
        uint4 o;
        o.x = pack2(a.x, a.y); o.y = pack2(a.z, a.w);
        o.z = pack2(b.x, b.y); o.w = pack2(b.z, b.w);
        *(uint4*)(xb + i * 8) = o;
    }
}

// Wt[n*ostride + ooffs + k] = W[k][n], bf16
__global__ void wprep_k(const float* __restrict__ W, unsigned short* __restrict__ Wt,
                        int K, int Ncols, int ostride, int ooffs){
    int idx = blockIdx.x * 256 + threadIdx.x;
    if (idx < K * Ncols){
        int k = idx / Ncols, n = idx - k * Ncols;
        Wt[(size_t)n * ostride + ooffs + k] = f2bf_u(W[idx]);
    }
}

// ---------------- CSR build ----------------
__global__ void hist_k(const int* __restrict__ dst, int* __restrict__ indeg, int E){
    int i = blockIdx.x * 256 + threadIdx.x;
    if (i < E) atomicAdd(&indeg[dst[i]], 1);
}

__global__ void scan1_k(const int* __restrict__ indeg, int* __restrict__ csum, int N){
    __shared__ int sd[256];
    const int base = blockIdx.x * 2048;
    int s = 0;
    for (int j = 0; j < 8; ++j){
        int i = base + j * 256 + threadIdx.x;
        if (i < N) s += indeg[i];
    }
    sd[threadIdx.x] = s; __syncthreads();
    for (int d = 128; d > 0; d >>= 1){
        if (threadIdx.x < d) sd[threadIdx.x] += sd[threadIdx.x + d];
        __syncthreads();
    }
    if (threadIdx.x == 0) csum[blockIdx.x] = sd[0];
}

__global__ void scan2_k(int* csum, int nch){
    if (threadIdx.x == 0 && blockIdx.x == 0){
        int run = 0;
        for (int i = 0; i < nch; ++i){ int v = csum[i]; csum[i] = run; run += v; }
    }
}

__global__ void scan3_k(const int* __restrict__ indeg, const int* __restrict__ csum,
                        int* __restrict__ offsets, int* __restrict__ cursor, int N, int E){
    __shared__ int ss[256];
    const int base = blockIdx.x * 2048;
    int v[8], pre[8]; int s = 0;
    const int tb = base + threadIdx.x * 8;
#pragma unroll
    for (int j = 0; j < 8; ++j){
        int i = tb + j;
        v[j] = (i < N) ? indeg[i] : 0;
        pre[j] = s; s += v[j];
    }
    ss[threadIdx.x] = s; __syncthreads();
    for (int d = 1; d < 256; d <<= 1){
        int t_ = (threadIdx.x >= d) ? ss[threadIdx.x - d] : 0;
        __syncthreads();
        ss[threadIdx.x] += t_;
        __syncthreads();
    }
    const int excl = ss[threadIdx.x] - s + csum[blockIdx.x];
#pragma unroll
    for (int j = 0; j < 8; ++j){
        int i = tb + j;
        if (i < N){ offsets[i] = excl + pre[j]; cursor[i] = excl + pre[j]; }
    }
    if (blockIdx.x == 0 && threadIdx.x == 0) offsets[N] = E;
}

__global__ void fill_k(const int* __restrict__ src, const int* __restrict__ dst,
                       int* __restrict__ cursor, int* __restrict__ esrc, int E){
    int i = blockIdx.x * 256 + threadIdx.x;
    if (i < E){
        int d = dst[i];
        int pos = atomicAdd(&cursor[d], 1);
        esrc[pos] = src[i];
    }
}

// ---------------- aggregation into AG[:,0:256]; hbn = AG+256, both row-stride 512 ----------------
__global__ __launch_bounds__(256)
void agg_k(const unsigned short* __restrict__ hbn, const int* __restrict__ offsets,
           const int* __restrict__ esrc, unsigned short* __restrict__ aggout, int N){
    const int lane = threadIdx.x & 63;
    const int node = blockIdx.x * 4 + (threadIdx.x >> 6);
    if (node >= N) return;
    const int off = offsets[node];
    const int end = offsets[node + 1];
    float a0 = 0.f, a1 = 0.f, a2 = 0.f, a3 = 0.f;
    for (int c = off; c < end; c += 64){
        const int e = c + lane;
        int sl = (e < end) ? esrc[e] : 0;
        const int cnt = min(64, end - c);
        for (int j = 0; j < cnt; ++j){
            const int s = __shfl(sl, j);
            const uint2 u = *(const uint2*)(hbn + (size_t)s * 512 + lane * 4);
            a0 += bf_lo(u.x); a1 += bf_hi(u.x);
            a2 += bf_lo(u.y); a3 += bf_hi(u.y);
        }
    }
    uint2 o; o.x = pack2(a0, a1); o.y = pack2(a2, a3);
    *(uint2*)(aggout + (size_t)node * 512 + lane * 4) = o;
}

// ---------------- GEMM v3 (m97 structure, swapped operands) ----------------
// C[M][NCOLS] = A[M][K](bf16) @ W, W given as Bt[n][k] bf16 row-stride K.
// Tile BM=128 x BN=64 x BK=64; 4 waves, wave w owns rows [w*32, w*32+32).
// Operand swap: A-operand = weight frag (m-index = out-col), B-operand = X frag
// (n-index = node row). D: col(lane&15)=node, row(q4*4+r)=out-col → lane holds 4
// consecutive out-cols of one node → 8B stores.
template<int K, bool GELU_OUT>
__global__ __launch_bounds__(256)
void gemm3_k(const unsigned short* __restrict__ A, const unsigned short* __restrict__ Bt,
             const float* __restrict__ bias, unsigned short* __restrict__ Cp,
             long M, int NCOLS){
    __shared__ unsigned short Xs[128 * 64];   // [row][k]
    __shared__ unsigned short Ws[64 * 64];    // [col][k]
    const int t    = threadIdx.x;
    const int lane = t & 63;
    const int w    = t >> 6;
    const int r16  = lane & 15;
    const int q4   = lane >> 4;
    const long mbase = (long)blockIdx.x * 128;
    const int  cb    = blockIdx.y * 64;

    floatx4 acc[4][2];
#pragma unroll
    for (int ai = 0; ai < 4; ++ai)
#pragma unroll
        for (int bi = 0; bi < 2; ++bi) acc[ai][bi] = (floatx4)0.f;

    // staging lane geometry: 16B per lane; row = 8 rows/wave-iter
    const int lrow = w * 8 + (lane >> 3);
    const int lk   = (lane & 7) * 8;
    const unsigned short* ga = A  + (size_t)(mbase + lrow) * K + lk;
    const unsigned short* gb = Bt + (size_t)(cb + lrow) * K + lk;
    unsigned short* lx = Xs + w * 512 + lane * 8;
    unsigned short* lw = Ws + w * 512 + lane * 8;

    for (int kt = 0; kt < K; kt += 64){
#pragma unroll
        for (int i = 0; i < 4; ++i)
            gload_lds16(ga + (size_t)i * 32 * K + kt, lx + i * 2048);
#pragma unroll
        for (int j = 0; j < 2; ++j)
            gload_lds16(gb + (size_t)j * 32 * K + kt, lw + j * 2048);
        asm volatile("s_waitcnt vmcnt(0)" ::: "memory");
        __syncthreads();
#pragma unroll
        for (int kc = 0; kc < 64; kc += 32){
            bf16x8 wf[4], xf[2];
#pragma unroll
            for (int ai = 0; ai < 4; ++ai)
                wf[ai] = *(const bf16x8*)(Ws + (ai * 16 + r16) * 64 + kc + q4 * 8);
#pragma unroll
            for (int bi = 0; bi < 2; ++bi)
                xf[bi] = *(const bf16x8*)(Xs + (w * 32 + bi * 16 + r16) * 64 + kc + q4 * 8);
#pragma unroll
            for (int ai = 0; ai < 4; ++ai)
#pragma unroll
                for (int bi = 0; bi < 2; ++bi)
                    acc[ai][bi] = __builtin_amdgcn_mfma_f32_16x16x32_bf16(
                        wf[ai], xf[bi], acc[ai][bi], 0, 0, 0);
        }
        __syncthreads();
    }

    // epilogue: bias (+gelu), 8B vector stores
    float4 bv[4];
#pragma unroll
    for (int ai = 0; ai < 4; ++ai)
        bv[ai] = *(const float4*)(bias + cb + ai * 16 + q4 * 4);
#pragma unroll
    for (int bi = 0; bi < 2; ++bi){
        long node = mbase + w * 32 + bi * 16 + r16;
        if (node < M){
            unsigned short* cp = Cp + (size_t)node * NCOLS + cb;
#pragma unroll
            for (int ai = 0; ai < 4; ++ai){
                float v0 = acc[ai][bi][0] + bv[ai].x;
                float v1 = acc[ai][bi][1] + bv[ai].y;
                float v2 = acc[ai][bi][2] + bv[ai].z;
                float v3 = acc[ai][bi][3] + bv[ai].w;
                if constexpr (GELU_OUT){
                    v0 = gelu_f(v0); v1 = gelu_f(v1); v2 = gelu_f(v2); v3 = gelu_f(v3);
                }
                uint2 o; o.x = pack2(v0, v1); o.y = pack2(v2, v3);
                *(uint2*)(cp + ai * 16 + q4 * 4) = o;
            }
        }
    }
}

// ---------------- column stats: gsum[c] += sum rows, gsq[c] += sum rows^2 ----------------
template<int NCOLS>
__global__ void colstats_k(const unsigned short* __restrict__ in,
                           float* __restrict__ gsum, float* __restrict__ gsq, long nrows){
    constexpr int TPR  = NCOLS / 8;
    constexpr int BDIM = (NCOLS == 192) ? 192 : 256;
    constexpr int ROWS = BDIM / TPR;
    __shared__ float sS[ROWS * NCOLS], sQ[ROWS * NCOLS];
    const int t  = threadIdx.x;
    const int c8 = (t % TPR) * 8;
    const int r  = t / TPR;
    float s[8], q[8];
#pragma unroll
    for (int j = 0; j < 8; ++j){ s[j] = 0.f; q[j] = 0.f; }
    for (long row = (long)blockIdx.x * ROWS + r; row < nrows; row += (long)gridDim.x * ROWS){
        uint4 u = *(const uint4*)(in + row * NCOLS + c8);
        float v[8];
        v[0] = bf_lo(u.x); v[1] = bf_hi(u.x); v[2] = bf_lo(u.y); v[3] = bf_hi(u.y);
        v[4] = bf_lo(u.z); v[5] = bf_hi(u.z); v[6] = bf_lo(u.w); v[7] = bf_hi(u.w);
#pragma unroll
        for (int j = 0; j < 8; ++j){ s[j] += v[j]; q[j] += v[j] * v[j]; }
    }
#pragma unroll
    for (int j = 0; j < 8; ++j){ sS[r * NCOLS + c8 + j] = s[j]; sQ[r * NCOLS + c8 + j] = q[j]; }
    __syncthreads();
    for (int c = t; c < NCOLS; c += BDIM){
        float as = 0.f, aq = 0.f;
#pragma unroll
        for (int rr = 0; rr < ROWS; ++rr){ as += sS[rr * NCOLS + c]; aq += sQ[rr * NCOLS + c]; }
        atomicAdd(&gsum[c], as);
        atomicAdd(&gsq[c],  aq);
    }
}

// ---------------- BN apply (+gelu, +residual, strided out, fp32/bf16 out) ----------------
template<int NCOLS, bool GELU_OUT, bool RES, bool RES_F32, bool OUT_F32>
__global__ __launch_bounds__(256)
void bn_apply_k(const unsigned short* __restrict__ in, void* __restrict__ outv,
                const void* __restrict__ resv,
                const float* __restrict__ gsum, const float* __restrict__ gsq,
                const float* __restrict__ gamma, const float* __restrict__ beta,
                long nrows, int ostride, int ooffs, float invN){
    __shared__ float s_scale[NCOLS], s_shift[NCOLS];
    for (int c = threadIdx.x; c < NCOLS; c += 256){
        float mean = gsum[c] * invN;
        float var  = gsq[c] * invN - mean * mean;
        float sc   = gamma[c] * rsqrtf(var + 1e-5f);
        s_scale[c] = sc;
        s_shift[c] = beta[c] - mean * sc;
    }
    __syncthreads();
    long i8 = ((long)blockIdx.x * 256 + threadIdx.x) * 8;
    if (i8 >= nrows * (long)NCOLS) return;
    long row  = i8 / NCOLS;
    int  col0 = (int)(i8 - row * NCOLS);
    uint4 u = *(const uint4*)(in + i8);
    float v[8];
    v[0] = bf_lo(u.x); v[1] = bf_hi(u.x); v[2] = bf_lo(u.y); v[3] = bf_hi(u.y);
    v[4] = bf_lo(u.z); v[5] = bf_hi(u.z); v[6] = bf_lo(u.w); v[7] = bf_hi(u.w);
#pragma unroll
    for (int j = 0; j < 8; ++j){
        v[j] = v[j] * s_scale[col0 + j] + s_shift[col0 + j];
        if constexpr (GELU_OUT) v[j] = gelu_f(v[j]);
    }
    if constexpr (RES){
        if constexpr (RES_F32){
            const float4* rp = (const float4*)((const float*)resv + i8);
            float4 r0 = rp[0], r1 = rp[1];
            v[0] += r0.x; v[1] += r0.y; v[2] += r0.z; v[3] += r0.w;
            v[4] += r1.x; v[5] += r1.y; v[6] += r1.z; v[7] += r1.w;
        } else {
            uint4 r = *(const uint4*)((const unsigned short*)resv + i8);
            v[0] += bf_lo(r.x); v[1] += bf_hi(r.x); v[2] += bf_lo(r.y); v[3] += bf_hi(r.y);
            v[4] += bf_lo(r.z); v[5] += bf_hi(r.z); v[6] += bf_lo(r.w); v[7] += bf_hi(r.w);
        }
    }
    long opos = row * ostride + ooffs + col0;
    if constexpr (OUT_F32){
        float4* op = (float4*)((float*)outv + opos);
        op[0] = make_float4(v[0], v[1], v[2], v[3]);
        op[1] = make_float4(v[4], v[5], v[6], v[7]);
    } else {
        uint4 o;
        o.x = pack2(v[0], v[1]); o.y = pack2(v[2], v[3]);
        o.z = pack2(v[4], v[5]); o.w = pack2(v[6], v[7]);
        *(uint4*)((unsigned short*)outv + opos) = o;
    }
}

// ---------------- host ----------------
extern "C" void kernel_launch(void* const* d_in, const int* in_sizes, int n_in,
                              void* d_out, int out_size, void* d_ws, size_t ws_size,
                              hipStream_t stream){
    const int C = 192, GH = 256, FH = 512;
    const float* x    = (const float*)d_in[0];
    const int*   ei   = (const int*)d_in[1];
    const float* Wg1  = (const float*)d_in[2];
    const float* bg1  = (const float*)d_in[3];
    const float* gg1  = (const float*)d_in[4];
    const float* beg1 = (const float*)d_in[5];
    const float* Wrel = (const float*)d_in[6];
    const float* brel = (const float*)d_in[7];
    const float* Wroot= (const float*)d_in[8];
    const float* Wg2  = (const float*)d_in[9];
    const float* bg2  = (const float*)d_in[10];
    const float* gg2  = (const float*)d_in[11];
    const float* beg2 = (const float*)d_in[12];
    const float* Wf1  = (const float*)d_in[13];
    const float* bf1  = (const float*)d_in[14];
    const float* gf1  = (const float*)d_in[15];
    const float* bef1 = (const float*)d_in[16];
    const float* Wf2  = (const float*)d_in[17];
    const float* bf2  = (const float*)d_in[18];
    const float* gf2  = (const float*)d_in[19];
    const float* bef2 = (const float*)d_in[20];

    const int N = in_sizes[0] / C;
    const int E = in_sizes[1] / 2;
    const int* e_src = ei;
    const int* e_dst = ei + E;

    // ---- workspace arena (~214 MB). Big A-source buffers placed BEFORE the
    // int buffers so gemm3's ≤130 KB staging over-read stays in-arena. ----
    char* wp = (char*)d_ws;
    auto carve = [&](size_t bytes) -> void* {
        void* p = (void*)wp; wp += (bytes + 255) & ~(size_t)255; return p;
    };
    unsigned short* wt_g1 = (unsigned short*)carve((size_t)GH * C * 2);     // [256][192]
    unsigned short* wt_rr = (unsigned short*)carve((size_t)GH * 512 * 2);   // [256][512] = [Wrel^T|Wroot^T]
    unsigned short* wt_g2 = (unsigned short*)carve((size_t)C * GH * 2);     // [192][256]
    unsigned short* wt_f1 = (unsigned short*)carve((size_t)FH * C * 2);     // [512][192]
    unsigned short* wt_f2 = (unsigned short*)carve((size_t)C * FH * 2);     // [192][512]
    float* stats = (float*)carve(2 * (size_t)(GH + C + FH + C) * 4);
    float* sum1 = stats;        float* sq1 = sum1 + GH;
    float* sum2 = sq1 + GH;     float* sq2 = sum2 + C;
    float* sum3 = sq2 + C;      float* sq3 = sum3 + FH;
    float* sum4 = sq3 + FH;     float* sq4 = sum4 + C;
    // buf0 [N,512]: h1[N,256] -> g[N,256] -> f1/g2[N,512]
    unsigned short* buf0  = (unsigned short*)carve((size_t)N * 512 * 2);
    // bufAG [N,512]: x_bf[N,192] (dies at g1) -> AG=[agg|hbn] -> h2/x2[N,192]@0, h4[N,192]@N*192
    unsigned short* bufAG = (unsigned short*)carve((size_t)N * 512 * 2);
    int* indeg   = (int*)carve((size_t)N * 4);
    int* offsets = (int*)carve((size_t)(N + 1) * 4);
    int* cursor  = (int*)carve((size_t)(N + 1) * 4);
    const int nch = (N + 2047) / 2048;
    int* csum    = (int*)carve((size_t)nch * 4);
    int* esrc    = (int*)carve((size_t)E * 4);
    unsigned short* x_bf = bufAG;                       // [N,192] overlay, dead before AG written
    unsigned short* h1  = buf0;
    unsigned short* g   = buf0;
    unsigned short* f1  = buf0;                          // also g2 (in-place BN)
    unsigned short* AG  = bufAG;
    unsigned short* h2  = bufAG;                         // also x2 (in-place BN+res)
    unsigned short* h4  = bufAG + (size_t)N * C;
    (void)ws_size; (void)n_in; (void)out_size;

    const float invN = 1.0f / (float)N;
    const int GB = (N + 127) / 128;   // gemm3 grid.x
    const int EB = (E + 255) / 256;

    // weight prep
    wprep_k<<<(C * GH + 255) / 256, 256, 0, stream>>>(Wg1, wt_g1, C, GH, C, 0);
    wprep_k<<<(GH * GH + 255) / 256, 256, 0, stream>>>(Wrel, wt_rr, GH, GH, 512, 0);
    wprep_k<<<(GH * GH + 255) / 256, 256, 0, stream>>>(Wroot, wt_rr, GH, GH, 512, GH);
    wprep_k<<<(GH * C + 255) / 256, 256, 0, stream>>>(Wg2, wt_g2, GH, C, GH, 0);
    wprep_k<<<(C * FH + 255) / 256, 256, 0, stream>>>(Wf1, wt_f1, C, FH, C, 0);
    wprep_k<<<(FH * C + 255) / 256, 256, 0, stream>>>(Wf2, wt_f2, FH, C, FH, 0);

    const int nstats = 2 * (GH + C + FH + C);
    zero_k<<<(nstats + 255) / 256, 256, 0, stream>>>((int*)stats, nstats);
    zero_k<<<(N + 255) / 256, 256, 0, stream>>>(indeg, N);

    // CSR build
    hist_k<<<EB, 256, 0, stream>>>(e_dst, indeg, E);
    scan1_k<<<nch, 256, 0, stream>>>(indeg, csum, N);
    scan2_k<<<1, 64, 0, stream>>>(csum, nch);
    scan3_k<<<nch, 256, 0, stream>>>(indeg, csum, offsets, cursor, N, E);
    fill_k<<<EB, 256, 0, stream>>>(e_src, e_dst, cursor, esrc, E);

    // x -> bf16 (for g1 GEMM A-input)
    xcast_k<<<(int)(((size_t)N * C / 8 + 255) / 256), 256, 0, stream>>>(x, x_bf, (long)N * C / 8);

    // ---- Grapher ----
    // h1 = x @ Wg1 + bg1
    gemm3_k<192, false><<<dim3(GB, GH / 64), 256, 0, stream>>>(x_bf, wt_g1, bg1, h1, N, GH);
    colstats_k<256><<<512, 256, 0, stream>>>(h1, sum1, sq1, N);
    // hbn = BN(h1) -> AG[:,256:512]   (x_bf dies here)
    bn_apply_k<256, false, false, false, false><<<(int)(((size_t)N * GH / 8 + 255) / 256), 256, 0, stream>>>(
        h1, AG, nullptr, sum1, sq1, gg1, beg1, N, 512, 256, invN);
    // agg -> AG[:,0:256]
    agg_k<<<(N + 3) / 4, 256, 0, stream>>>(AG + 256, offsets, esrc, AG, N);
    // g = gelu([agg|hbn] @ [Wrel;Wroot] + brel)
    gemm3_k<512, true><<<dim3(GB, GH / 64), 256, 0, stream>>>(AG, wt_rr, brel, g, N, GH);
    // h2 = g @ Wg2 + bg2
    gemm3_k<256, false><<<dim3(GB, C / 64), 256, 0, stream>>>(g, wt_g2, bg2, h2, N, C);
    colstats_k<192><<<512, 192, 0, stream>>>(h2, sum2, sq2, N);
    // x2 = BN(h2) + x   (in-place)
    bn_apply_k<192, false, true, true, false><<<(int)(((size_t)N * C / 8 + 255) / 256), 256, 0, stream>>>(
        h2, h2, x, sum2, sq2, gg2, beg2, N, 192, 0, invN);

    // ---- FFN ----
    // f1 = x2 @ Wf1 + bf1
    gemm3_k<192, false><<<dim3(GB, FH / 64), 256, 0, stream>>>(h2, wt_f1, bf1, f1, N, FH);
    colstats_k<512><<<512, 256, 0, stream>>>(f1, sum3, sq3, N);
    // g2 = gelu(BN(f1))  (in-place)
    bn_apply_k<512, true, false, false, false><<<(int)(((size_t)N * FH / 8 + 255) / 256), 256, 0, stream>>>(
        f1, f1, nullptr, sum3, sq3, gf1, bef1, N, 512, 0, invN);
    // h4 = g2 @ Wf2 + bf2
    gemm3_k<512, false><<<dim3(GB, C / 64), 256, 0, stream>>>(f1, wt_f2, bf2, h4, N, C);
    colstats_k<192><<<512, 192, 0, stream>>>(h4, sum4, sq4, N);
    // out = BN(h4) + x2  (fp32 out)
    bn_apply_k<192, false, true, false, true><<<(int)(((size_t)N * C / 8 + 255) / 256), 256, 0, stream>>>(
        h4, d_out, h2, sum4, sq4, gf2, bef2, N, 192, 0, invN);
}